// Round 20
// baseline (172.192 us; speedup 1.0000x reference)
//
#include <hip/hip_runtime.h>
#include <hip/hip_bf16.h>

typedef _Float16 f16;
typedef _Float16 f16x4 __attribute__((ext_vector_type(4)));
typedef _Float16 f16x8 __attribute__((ext_vector_type(8)));
typedef float f32x4 __attribute__((ext_vector_type(4)));

constexpr int BATCH = 4, C = 512, CQ = 128, N = 4096;
constexpr int OALL = 768; // stacked outputs: f(128) + k(128) + v(512)

// workspace layout (bytes)
constexpr size_t WS_FT   = 0;                                      // f16 [B][N][128]       4 MB
constexpr size_t WS_KT   = WS_FT   + (size_t)BATCH * N * CQ * 2;   // f16 [B][N][128]       4 MB (K, row-major)
constexpr size_t WS_V    = WS_KT   + (size_t)BATCH * N * CQ * 2;   // f16 [B][C/16][N/8][16][8] 16 MB (tiled V)
constexpr size_t WS_WALL = WS_V    + (size_t)BATCH * C * N * 2;    // f16 [768][512]
constexpr size_t WS_BALL = WS_WALL + (size_t)OALL * C * 2;         // f32 [768]

// ---------------------------------------------------------------- stacked weights->fp16
__global__ void prep_weights(const float* __restrict__ Wf_w, const float* __restrict__ Wf_b,
                             const float* __restrict__ Wh_w, const float* __restrict__ Wh_b,
                             const float* __restrict__ Wl_w, const float* __restrict__ Wl_b,
                             f16* __restrict__ wall, float* __restrict__ ball) {
    int i = blockIdx.x * 256 + threadIdx.x;                 // grid covers 768*512
    if (i < OALL * C) {
        int o = i >> 9, c = i & 511;
        float v = (o < 128) ? Wf_w[o * C + c]
                : (o < 256) ? Wh_w[(o - 128) * C + c]
                            : Wl_w[(o - 256) * C + c];
        wall[i] = (f16)v;
    }
    if (i < OALL)
        ball[i] = (i < 128) ? Wf_b[i] : (i < 256) ? Wh_b[i - 128] : Wl_b[i - 256];
}

// ---------------------------------------------------------------- fused projections (v16, unchanged champion)
__global__ void __launch_bounds__(512) proj_all(const float* __restrict__ x, const f16* __restrict__ wall,
                                                const float* __restrict__ ball,
                                                f16* __restrict__ ft, f16* __restrict__ kt,
                                                f16* __restrict__ v) {
    __shared__ __align__(16) f16 xl[64][72];   // 9 KB, 72-pad for b128 alignment
    const int tid = threadIdx.x;
    const int wv  = tid >> 6;
    const int lane = tid & 63;
    const int li = lane & 15, lg = lane >> 4;
    const int b  = blockIdx.x >> 6;
    const int n0 = (blockIdx.x & 63) * 64;
    const int ob = wv * 96;                    // wave's output slice (6 frags of 16)
    const int nn = tid & 63, cg = tid >> 6;    // staging decode: 8 c-groups of 8

    f32x4 acc[6][4] = {};                      // [o-frag][n-frag]
    for (int ch = 0; ch < 8; ++ch) {
        __syncthreads();                       // xl free (readers of prev chunk done)
        {   // stage 64c x 64n f32 -> xl[n][c] f16 (global reads coalesced along n)
            const float* xs = x + ((size_t)(b * C) + ch * 64 + cg * 8) * N + n0 + nn;
#pragma unroll
            for (int r = 0; r < 8; ++r)
                xl[nn][cg * 8 + r] = (f16)xs[(size_t)r * N];
        }
        __syncthreads();
#pragma unroll
        for (int ks = 0; ks < 2; ++ks) {
            f16x8 xfr[4];
#pragma unroll
            for (int nf = 0; nf < 4; ++nf)
                xfr[nf] = *(const f16x8*)(&xl[nf * 16 + li][ks * 32 + lg * 8]);
#pragma unroll
            for (int of = 0; of < 6; ++of) {
                f16x8 wfr = *(const f16x8*)(wall + (size_t)(ob + of * 16 + li) * C + ch * 64 + ks * 32 + lg * 8);
#pragma unroll
                for (int nf = 0; nf < 4; ++nf)
                    acc[of][nf] = __builtin_amdgcn_mfma_f32_16x16x32_f16(xfr[nf], wfr, acc[of][nf], 0, 0, 0);
            }
        }
    }
    // epilogue: D col(li) = o (B-operand row), D row (lg*4+r) = n (A-operand row)
#pragma unroll
    for (int of = 0; of < 6; ++of) {
        const int o = ob + of * 16 + li;
        const float bias = ball[o];
#pragma unroll
        for (int nf = 0; nf < 4; ++nf)
#pragma unroll
            for (int r = 0; r < 4; ++r) {
                const int n = n0 + nf * 16 + lg * 4 + r;
                const f16 val = (f16)(acc[of][nf][r] + bias);
                if (o < 128) {
                    ft[(size_t)(b * N + n) * CQ + o] = val;
                } else if (o < 256) {
                    const int ck = o - 128;
                    kt[((size_t)b * N + n) * 128 + ck] = val;
                } else {
                    const int c = o - 256;
                    v[(((size_t)b * 32 + (c >> 4)) * 512 + (n >> 3)) * 128 + (c & 15) * 8 + (n & 7)] = val;
                }
            }
    }
}

// ---------------------------------------------------------------- flash attention + residual (v20)
// = v17 champion (direct-register K, 2 barriers, shared-stats softmax, rolling V
// prefetch, scalar stat layout) with KVBLK 128 -> 256: per-iteration fixed costs
// (2 barriers, stat combines, T13 block, loop overhead) halve; MFMA/exp/V per-j
// unchanged. K stays at 32 VGPR via slice rotation: kfB(slice1) loads hide under
// QK-slice0's MFMAs; kfA reloads next tile's slice0 under QK-slice1.
__global__ void __launch_bounds__(512, 2) attn(const f16* __restrict__ ft, const f16* __restrict__ kt,
                                               const f16* __restrict__ v,
                                               const float* __restrict__ x, const float* __restrict__ alphap,
                                               float* __restrict__ out) {
    __shared__ __align__(16) f16 pbuf[64 * 256];       // 32 KB shared P
    __shared__ float smax[8][4][16];
    __shared__ float ssum[8][4][16];

    const int tid  = threadIdx.x;
    const int wv   = tid >> 6;
    const int lane = tid & 63;
    const int li = lane & 15, lg = lane >> 4;
    const int swl = li & 7;
    // XCD-pinning: under blk%8 round-robin, each XCD sees a single batch
    const int v0 = blockIdx.x;
    const int b  = (v0 & 7) >> 1;
    const int it = ((v0 & 1) << 5) | (v0 >> 3);
    const int i0 = it * 64;
    const int c0 = wv * 64;

    // F fragments (B operand of swapped QK): col=i, k=ck; 4 i-frags
    f16x8 fb[4][4];
#pragma unroll
    for (int f = 0; f < 4; ++f) {
        const f16* fp = ft + (size_t)(b * N + i0 + f * 16 + li) * CQ + lg * 8;
#pragma unroll
        for (int ks = 0; ks < 4; ++ks) fb[f][ks] = *(const f16x8*)(fp + ks * 32);
    }

    // direct-register K: wave owns rows [wv*32, wv*32+32) of each 256-j tile.
    // lane reads row (tile*256 + wv*32 + sl*16 + li), cols ks*32 + lg*8.
    const f16* kL = kt + ((size_t)b * N + wv * 32 + li) * 128 + lg * 8;
    f16x8 kfA[4], kfB[4];
#pragma unroll
    for (int ks = 0; ks < 4; ++ks) kfA[ks] = *(const f16x8*)(kL + ks * 32);   // tile0 slice0

    // tiled V base: j-block jb = t*32 + ph*4 + lg covers 8 j each
    const f16* vb2 = v + (((size_t)b * 32 + wv * 4) * 512 + lg) * 128 + li * 8;
    f32x4 oacc[4][4] = {};                       // [c-frag][i-frag]
    float ms[4] = {-1e30f, -1e30f, -1e30f, -1e30f};
    float ls[4] = {0.f, 0.f, 0.f, 0.f};

    for (int t = 0; t < 16; ++t) {
        const size_t jb0 = (size_t)t * 32;
        const size_t ktile = (size_t)t * 256 * 128;
        // (a0) issue slice-1 K loads (latency covered by slice-0 QK MFMAs)
#pragma unroll
        for (int ks = 0; ks < 4; ++ks)
            kfB[ks] = *(const f16x8*)(kL + ktile + (size_t)16 * 128 + ks * 32);
        // (b0) QK slice 0 (j = wv*32 + lg*4 + r), all 4 i-frags
        f32x4 s[2][4] = {};
        __builtin_amdgcn_s_setprio(1);
#pragma unroll
        for (int ks = 0; ks < 4; ++ks)
#pragma unroll
            for (int f = 0; f < 4; ++f)
                s[0][f] = __builtin_amdgcn_mfma_f32_16x16x32_f16(kfA[ks], fb[f][ks], s[0][f], 0, 0, 0);
        __builtin_amdgcn_s_setprio(0);
        // (a1) reload kfA with NEXT tile's slice 0 (rest of iteration covers latency)
        const size_t knext = (size_t)((t < 15) ? (t + 1) : 0) * 256 * 128;
#pragma unroll
        for (int ks = 0; ks < 4; ++ks)
            kfA[ks] = *(const f16x8*)(kL + knext + ks * 32);
        // (b1) QK slice 1 (j = wv*32 + 16 + lg*4 + r)
        __builtin_amdgcn_s_setprio(1);
#pragma unroll
        for (int ks = 0; ks < 4; ++ks)
#pragma unroll
            for (int f = 0; f < 4; ++f)
                s[1][f] = __builtin_amdgcn_mfma_f32_16x16x32_f16(kfB[ks], fb[f][ks], s[1][f], 0, 0, 0);
        __builtin_amdgcn_s_setprio(0);

        // (c) wave-local max over 32 j per query; publish
#pragma unroll
        for (int f = 0; f < 4; ++f) {
            float t0 = fmaxf(fmaxf(s[0][f][0], s[0][f][1]), fmaxf(s[0][f][2], s[0][f][3]));
            float t1 = fmaxf(fmaxf(s[1][f][0], s[1][f][1]), fmaxf(s[1][f][2], s[1][f][3]));
            t0 = fmaxf(t0, t1);
            t0 = fmaxf(t0, __shfl_xor(t0, 16));
            t0 = fmaxf(t0, __shfl_xor(t0, 32));
            if (lane < 16) smax[wv][f][li] = t0;
        }
        // V prefetch phase 0 (latency hides under B1)
        f16x8 va[2][4];
#pragma unroll
        for (int cf = 0; cf < 4; ++cf) va[0][cf] = *(const f16x8*)(vb2 + ((size_t)cf * 512 + jb0) * 128);
        __syncthreads();   // B1: max stats visible
        // (d) tile max over 8 waves (broadcast reads)
        float gm[4];
#pragma unroll
        for (int f = 0; f < 4; ++f) {
            float m0 = smax[0][f][li];
#pragma unroll
            for (int w = 1; w < 8; ++w) m0 = fmaxf(m0, smax[w][f][li]);
            gm[f] = m0;
        }
        // V prefetch phase 1
#pragma unroll
        for (int cf = 0; cf < 4; ++cf) va[1][cf] = *(const f16x8*)(vb2 + ((size_t)cf * 512 + jb0 + 4) * 128);
        // T13 deferred rescale (identical decision in all waves: shared stats)
#pragma unroll
        for (int f = 0; f < 4; ++f) {
            if (!__all(gm[f] <= ms[f] + 8.0f)) {
                float mn = fmaxf(ms[f], gm[f]), sc = __expf(ms[f] - mn);
                ms[f] = mn; ls[f] *= sc;
#pragma unroll
                for (int cf = 0; cf < 4; ++cf) oacc[cf][f] *= sc;
            }
        }
        // (e) exp (8 j per lane per f, 2 slices) + P write + partial sums
        float ps[4];
#pragma unroll
        for (int f = 0; f < 4; ++f) {
            float p0 = 0.f;
#pragma unroll
            for (int sl = 0; sl < 2; ++sl) {
                const int jl = wv * 32 + sl * 16 + lg * 4;
                const int gg = (jl >> 3) ^ swl;
                f16x4 pk;
#pragma unroll
                for (int r = 0; r < 4; ++r) { float p = __expf(s[sl][f][r] - ms[f]); p0 += p; pk[r] = (f16)p; }
                *(f16x4*)(&pbuf[(f * 16 + li) * 256 + gg * 8 + (jl & 7)]) = pk;
            }
            ps[f] = p0;
        }
#pragma unroll
        for (int f = 0; f < 4; ++f) {
            ps[f] += __shfl_xor(ps[f], 16);
            ps[f] += __shfl_xor(ps[f], 32);
        }
        if (lane < 16) {
#pragma unroll
            for (int f = 0; f < 4; ++f) ssum[wv][f][li] = ps[f];
        }
        __syncthreads();   // B2: P + ssum visible
        // (f) accumulate l from shared partial sums
#pragma unroll
        for (int f = 0; f < 4; ++f) {
            float a0 = 0.f;
#pragma unroll
            for (int w = 0; w < 8; ++w) a0 += ssum[w][f][li];
            ls[f] += a0;
        }
        // (g) PV over 256 j: 8 phases, rolling 2-deep V prefetch
#pragma unroll
        for (int ph = 0; ph < 8; ++ph) {
            const int cur = ph & 1;
            const int g = (ph * 4 + lg) ^ swl;
            f16x8 pb[4];
#pragma unroll
            for (int f = 0; f < 4; ++f)
                pb[f] = *(const f16x8*)(&pbuf[(f * 16 + li) * 256 + g * 8]);
            f16x8 vv0 = va[cur][0], vv1 = va[cur][1], vv2 = va[cur][2], vv3 = va[cur][3];
            if (ph < 6) {
#pragma unroll
                for (int cf = 0; cf < 4; ++cf)
                    va[cur][cf] = *(const f16x8*)(vb2 + ((size_t)cf * 512 + jb0 + (ph + 2) * 4) * 128);
            }
            __builtin_amdgcn_s_setprio(1);
#pragma unroll
            for (int f = 0; f < 4; ++f) {
                oacc[0][f] = __builtin_amdgcn_mfma_f32_16x16x32_f16(vv0, pb[f], oacc[0][f], 0, 0, 0);
                oacc[1][f] = __builtin_amdgcn_mfma_f32_16x16x32_f16(vv1, pb[f], oacc[1][f], 0, 0, 0);
                oacc[2][f] = __builtin_amdgcn_mfma_f32_16x16x32_f16(vv2, pb[f], oacc[2][f], 0, 0, 0);
                oacc[3][f] = __builtin_amdgcn_mfma_f32_16x16x32_f16(vv3, pb[f], oacc[3][f], 0, 0, 0);
            }
            __builtin_amdgcn_s_setprio(0);
        }
        // pbuf reads of tile t finish before B1(t+1); writes of t+1 occur after it
    }

    // epilogue: O[c][i], i coalesced over li; + residual
    const float alpha = alphap[0];
#pragma unroll
    for (int f = 0; f < 4; ++f) {
        const float invf = alpha / ls[f];
        const float* xp = x + (size_t)(b * C + c0) * N + i0 + f * 16 + li;
        float* op = out + (size_t)(b * C + c0) * N + i0 + f * 16 + li;
#pragma unroll
        for (int cf = 0; cf < 4; ++cf)
#pragma unroll
            for (int r = 0; r < 4; ++r) {
                const int cl = cf * 16 + lg * 4 + r;
                op[(size_t)cl * N] = oacc[cf][f][r] * invf + xp[(size_t)cl * N];
            }
    }
}

extern "C" void kernel_launch(void* const* d_in, const int* in_sizes, int n_in,
                              void* d_out, int out_size, void* d_ws, size_t ws_size,
                              hipStream_t stream) {
    const float* x     = (const float*)d_in[0];
    const float* Wf_w  = (const float*)d_in[1];
    const float* Wf_b  = (const float*)d_in[2];
    const float* Wh_w  = (const float*)d_in[3];
    const float* Wh_b  = (const float*)d_in[4];
    const float* Wl_w  = (const float*)d_in[5];
    const float* Wl_b  = (const float*)d_in[6];
    const float* alpha = (const float*)d_in[7];
    char* ws = (char*)d_ws;
    f16*   ftb  = (f16*)(ws + WS_FT);
    f16*   ktb  = (f16*)(ws + WS_KT);
    f16*   vb   = (f16*)(ws + WS_V);
    f16*   wall = (f16*)(ws + WS_WALL);
    float* ball = (float*)(ws + WS_BALL);
    float* out  = (float*)d_out;

    prep_weights<<<dim3((OALL * C + 255) / 256), dim3(256), 0, stream>>>(Wf_w, Wf_b, Wh_w, Wh_b, Wl_w, Wl_b, wall, ball);
    // fused projections: 4 b x 64 n-tiles = 256 blocks x 8 waves
    proj_all<<<dim3(256), dim3(512), 0, stream>>>(x, wall, ball, ftb, ktb, vb);
    // 4 b x 64 query-tiles(64q) = 256 blocks x 8 waves = 1 block/CU, XCD-pinned
    attn<<<dim3(256), dim3(512), 0, stream>>>(ftb, ktb, vb, x, alpha, out);
}

// Round 21
// 167.893 us; speedup vs baseline: 1.0256x; 1.0256x over previous
//
#include <hip/hip_runtime.h>
#include <hip/hip_bf16.h>

typedef _Float16 f16;
typedef _Float16 f16x4 __attribute__((ext_vector_type(4)));
typedef _Float16 f16x8 __attribute__((ext_vector_type(8)));
typedef float f32x4 __attribute__((ext_vector_type(4)));

constexpr int BATCH = 4, C = 512, CQ = 128, N = 4096;
constexpr int OALL = 768; // stacked outputs: f(128) + k(128) + v(512)

// workspace layout (bytes)
constexpr size_t WS_FT   = 0;                                      // f16 [B][N][128]       4 MB
constexpr size_t WS_KT   = WS_FT   + (size_t)BATCH * N * CQ * 2;   // f16 [B][N][128]       4 MB (K, row-major)
constexpr size_t WS_V    = WS_KT   + (size_t)BATCH * N * CQ * 2;   // f16 [B][C/16][N/8][16][8] 16 MB (tiled V)
constexpr size_t WS_WALL = WS_V    + (size_t)BATCH * C * N * 2;    // f16 [768][512]
constexpr size_t WS_BALL = WS_WALL + (size_t)OALL * C * 2;         // f32 [768]

// ---------------------------------------------------------------- stacked weights->fp16
__global__ void prep_weights(const float* __restrict__ Wf_w, const float* __restrict__ Wf_b,
                             const float* __restrict__ Wh_w, const float* __restrict__ Wh_b,
                             const float* __restrict__ Wl_w, const float* __restrict__ Wl_b,
                             f16* __restrict__ wall, float* __restrict__ ball) {
    int i = blockIdx.x * 256 + threadIdx.x;                 // grid covers 768*512
    if (i < OALL * C) {
        int o = i >> 9, c = i & 511;
        float v = (o < 128) ? Wf_w[o * C + c]
                : (o < 256) ? Wh_w[(o - 128) * C + c]
                            : Wl_w[(o - 256) * C + c];
        wall[i] = (f16)v;
    }
    if (i < OALL)
        ball[i] = (i < 128) ? Wf_b[i] : (i < 256) ? Wh_b[i - 128] : Wl_b[i - 256];
}

// ---------------------------------------------------------------- fused projections (v21: 256-thr blocks, 3 blocks/CU)
// Block = 256 thr (4 waves), one (b, 64n, 384-o half). Grid 512 = b(4) x nt(64) x oh(2).
// Same chunked LDS x-transpose as v16; with ~140 VGPR the CU fits ~3 blocks ->
// barrier convoys of one block overlap staging/MFMA of the others.
// Cost: x read twice (once per o-half); wall stays L2-resident.
__global__ void __launch_bounds__(256) proj_all(const float* __restrict__ x, const f16* __restrict__ wall,
                                                const float* __restrict__ ball,
                                                f16* __restrict__ ft, f16* __restrict__ kt,
                                                f16* __restrict__ v) {
    __shared__ __align__(16) f16 xl[64][72];   // 9 KB, 72-pad for b128 alignment
    const int tid = threadIdx.x;
    const int wv  = tid >> 6;                  // 0..3
    const int lane = tid & 63;
    const int li = lane & 15, lg = lane >> 4;
    const int v0 = blockIdx.x;
    const int b  = v0 >> 7;
    const int nt = (v0 >> 1) & 63;
    const int oh = v0 & 1;
    const int n0 = nt * 64;
    const int ob = oh * 384 + wv * 96;         // wave's output slice (6 frags of 16)
    const int nn = tid & 63, cg = tid >> 6;    // staging decode: 4 c-groups of 16

    f32x4 acc[6][4] = {};                      // [o-frag][n-frag]
    for (int ch = 0; ch < 8; ++ch) {
        __syncthreads();                       // xl free (readers of prev chunk done)
        {   // stage 64c x 64n f32 -> xl[n][c] f16 (global reads coalesced along n)
            const float* xs = x + ((size_t)(b * C) + ch * 64 + cg * 16) * N + n0 + nn;
#pragma unroll
            for (int r = 0; r < 16; ++r)
                xl[nn][cg * 16 + r] = (f16)xs[(size_t)r * N];
        }
        __syncthreads();
#pragma unroll
        for (int ks = 0; ks < 2; ++ks) {
            f16x8 xfr[4];
#pragma unroll
            for (int nf = 0; nf < 4; ++nf)
                xfr[nf] = *(const f16x8*)(&xl[nf * 16 + li][ks * 32 + lg * 8]);
#pragma unroll
            for (int of = 0; of < 6; ++of) {
                f16x8 wfr = *(const f16x8*)(wall + (size_t)(ob + of * 16 + li) * C + ch * 64 + ks * 32 + lg * 8);
#pragma unroll
                for (int nf = 0; nf < 4; ++nf)
                    acc[of][nf] = __builtin_amdgcn_mfma_f32_16x16x32_f16(xfr[nf], wfr, acc[of][nf], 0, 0, 0);
            }
        }
    }
    // epilogue: D col(li) = o (B-operand row), D row (lg*4+r) = n (A-operand row)
#pragma unroll
    for (int of = 0; of < 6; ++of) {
        const int o = ob + of * 16 + li;
        const float bias = ball[o];
#pragma unroll
        for (int nf = 0; nf < 4; ++nf)
#pragma unroll
            for (int r = 0; r < 4; ++r) {
                const int n = n0 + nf * 16 + lg * 4 + r;
                const f16 val = (f16)(acc[of][nf][r] + bias);
                if (o < 128) {
                    ft[(size_t)(b * N + n) * CQ + o] = val;
                } else if (o < 256) {
                    const int ck = o - 128;
                    kt[((size_t)b * N + n) * 128 + ck] = val;
                } else {
                    const int c = o - 256;
                    v[(((size_t)b * 32 + (c >> 4)) * 512 + (n >> 3)) * 128 + (c & 15) * 8 + (n & 7)] = val;
                }
            }
    }
}

// ---------------------------------------------------------------- flash attention + residual (v17 champion, verbatim)
// Direct-register K double-buffer (no LDS round-trip), 2 barriers/iter,
// shared-stats softmax (scalar broadcast layout), rolling V prefetch,
// 256 blocks XCD-pinned, tiled kt/V operands (1KB contiguous loads).
__global__ void __launch_bounds__(512, 2) attn(const f16* __restrict__ ft, const f16* __restrict__ kt,
                                               const f16* __restrict__ v,
                                               const float* __restrict__ x, const float* __restrict__ alphap,
                                               float* __restrict__ out) {
    __shared__ __align__(16) f16 pbuf[64 * 128];       // 16 KB shared P
    __shared__ float smax[8][4][16];
    __shared__ float ssum[8][4][16];

    const int tid  = threadIdx.x;
    const int wv   = tid >> 6;
    const int lane = tid & 63;
    const int li = lane & 15, lg = lane >> 4;
    const int swl = li & 7;
    // XCD-pinning: under blk%8 round-robin, each XCD sees a single batch
    const int v0 = blockIdx.x;
    const int b  = (v0 & 7) >> 1;
    const int it = ((v0 & 1) << 5) | (v0 >> 3);
    const int i0 = it * 64;
    const int c0 = wv * 64;

    // F fragments (B operand of swapped QK): col=i, k=ck; 4 i-frags
    f16x8 fb[4][4];
#pragma unroll
    for (int f = 0; f < 4; ++f) {
        const f16* fp = ft + (size_t)(b * N + i0 + f * 16 + li) * CQ + lg * 8;
#pragma unroll
        for (int ks = 0; ks < 4; ++ks) fb[f][ks] = *(const f16x8*)(fp + ks * 32);
    }

    // direct-register K: lane reads row (t*128 + wv*16 + li), cols ks*32 + lg*8
    const f16* kL = kt + ((size_t)b * N + wv * 16 + li) * 128 + lg * 8;
    f16x8 kf[4];
#pragma unroll
    for (int ks = 0; ks < 4; ++ks) kf[ks] = *(const f16x8*)(kL + ks * 32);

    // tiled V base: fragment (cf, phase) at vb2 + (cf*512 + t*16 + ph*4)*128
    const f16* vb2 = v + (((size_t)b * 32 + wv * 4) * 512 + lg) * 128 + li * 8;
    f32x4 oacc[4][4] = {};                       // [c-frag][i-frag]
    float ms[4] = {-1e30f, -1e30f, -1e30f, -1e30f};
    float ls[4] = {0.f, 0.f, 0.f, 0.f};

    for (int t = 0; t < 32; ++t) {
        const size_t jb0 = (size_t)t * 16;
        // (a) prefetch next K tile fragments into kfn (whole iteration of cover)
        f16x8 kfn[4];
        const size_t knext = (size_t)((t < 31) ? (t + 1) : 0) * 128 * 128;
#pragma unroll
        for (int ks = 0; ks < 4; ++ks) kfn[ks] = *(const f16x8*)(kL + knext + ks * 32);

        // (b) QK for this wave's 16-j slice, all 4 i-frags (K from registers)
        f32x4 s[4] = {};
        __builtin_amdgcn_s_setprio(1);
#pragma unroll
        for (int ks = 0; ks < 4; ++ks)
#pragma unroll
            for (int f = 0; f < 4; ++f)
                s[f] = __builtin_amdgcn_mfma_f32_16x16x32_f16(kf[ks], fb[f][ks], s[f], 0, 0, 0);
        __builtin_amdgcn_s_setprio(0);

        // (c) wave-local max per query (rows j = wv*16 + lg*4 + r)
#pragma unroll
        for (int f = 0; f < 4; ++f) {
            float t0 = fmaxf(fmaxf(s[f][0], s[f][1]), fmaxf(s[f][2], s[f][3]));
            t0 = fmaxf(t0, __shfl_xor(t0, 16));
            t0 = fmaxf(t0, __shfl_xor(t0, 32));
            if (lane < 16) smax[wv][f][li] = t0;
        }
        // V prefetch for PV kf=0, issued before the barrier (latency hides under it)
        f16x8 va[2][4];
#pragma unroll
        for (int cf = 0; cf < 4; ++cf) va[0][cf] = *(const f16x8*)(vb2 + ((size_t)cf * 512 + jb0) * 128);
        __syncthreads();   // B1: max stats visible
        // (d) tile max over 8 waves (broadcast reads)
        float gm[4];
#pragma unroll
        for (int f = 0; f < 4; ++f) {
            float m0 = smax[0][f][li];
#pragma unroll
            for (int w = 1; w < 8; ++w) m0 = fmaxf(m0, smax[w][f][li]);
            gm[f] = m0;
        }
        // V prefetch for kf=1
#pragma unroll
        for (int cf = 0; cf < 4; ++cf) va[1][cf] = *(const f16x8*)(vb2 + ((size_t)cf * 512 + jb0 + 4) * 128);
        // T13 deferred rescale (identical decision in all waves: shared stats)
#pragma unroll
        for (int f = 0; f < 4; ++f) {
            if (!__all(gm[f] <= ms[f] + 8.0f)) {
                float mn = fmaxf(ms[f], gm[f]), sc = __expf(ms[f] - mn);
                ms[f] = mn; ls[f] *= sc;
#pragma unroll
                for (int cf = 0; cf < 4; ++cf) oacc[cf][f] *= sc;
            }
        }
        // exp (this wave's 4 j per lane per f) + P write + partial sums
        const int jl = wv * 16 + lg * 4;
        const int gg = (jl >> 3) ^ swl;
        float ps[4];
#pragma unroll
        for (int f = 0; f < 4; ++f) {
            f16x4 pk;
            float p0 = 0.f;
#pragma unroll
            for (int r = 0; r < 4; ++r) { float p = __expf(s[f][r] - ms[f]); p0 += p; pk[r] = (f16)p; }
            *(f16x4*)(&pbuf[(f * 16 + li) * 128 + gg * 8 + (jl & 7)]) = pk;
            ps[f] = p0;
        }
#pragma unroll
        for (int f = 0; f < 4; ++f) {
            ps[f] += __shfl_xor(ps[f], 16);
            ps[f] += __shfl_xor(ps[f], 32);
        }
        if (lane < 16) {
#pragma unroll
            for (int f = 0; f < 4; ++f) ssum[wv][f][li] = ps[f];
        }
        __syncthreads();   // B2: P + ssum visible
        // (f) accumulate l from shared partial sums
#pragma unroll
        for (int f = 0; f < 4; ++f) {
            float a0 = 0.f;
#pragma unroll
            for (int w = 0; w < 8; ++w) a0 += ssum[w][f][li];
            ls[f] += a0;
        }
        // (g) PV over full 128 j, this wave's 64 channels; rolling V prefetch
#pragma unroll
        for (int kf2 = 0; kf2 < 4; ++kf2) {
            const int cur = kf2 & 1;
            const int g = (kf2 * 4 + lg) ^ swl;
            f16x8 pb[4];
#pragma unroll
            for (int f = 0; f < 4; ++f)
                pb[f] = *(const f16x8*)(&pbuf[(f * 16 + li) * 128 + g * 8]);
            f16x8 vv0 = va[cur][0], vv1 = va[cur][1], vv2 = va[cur][2], vv3 = va[cur][3];
            if (kf2 < 2) {
#pragma unroll
                for (int cf = 0; cf < 4; ++cf)
                    va[cur][cf] = *(const f16x8*)(vb2 + ((size_t)cf * 512 + jb0 + (kf2 + 2) * 4) * 128);
            }
            __builtin_amdgcn_s_setprio(1);
#pragma unroll
            for (int f = 0; f < 4; ++f) {
                oacc[0][f] = __builtin_amdgcn_mfma_f32_16x16x32_f16(vv0, pb[f], oacc[0][f], 0, 0, 0);
                oacc[1][f] = __builtin_amdgcn_mfma_f32_16x16x32_f16(vv1, pb[f], oacc[1][f], 0, 0, 0);
                oacc[2][f] = __builtin_amdgcn_mfma_f32_16x16x32_f16(vv2, pb[f], oacc[2][f], 0, 0, 0);
                oacc[3][f] = __builtin_amdgcn_mfma_f32_16x16x32_f16(vv3, pb[f], oacc[3][f], 0, 0, 0);
            }
            __builtin_amdgcn_s_setprio(0);
        }
        // roll K double-buffer
#pragma unroll
        for (int ks = 0; ks < 4; ++ks) kf[ks] = kfn[ks];
        // no 3rd barrier: next iter's B1 orders pbuf reuse (same proof as v12)
    }

    // epilogue: O[c][i], i coalesced over li; + residual
    const float alpha = alphap[0];
#pragma unroll
    for (int f = 0; f < 4; ++f) {
        const float invf = alpha / ls[f];
        const float* xp = x + (size_t)(b * C + c0) * N + i0 + f * 16 + li;
        float* op = out + (size_t)(b * C + c0) * N + i0 + f * 16 + li;
#pragma unroll
        for (int cf = 0; cf < 4; ++cf)
#pragma unroll
            for (int r = 0; r < 4; ++r) {
                const int cl = cf * 16 + lg * 4 + r;
                op[(size_t)cl * N] = oacc[cf][f][r] * invf + xp[(size_t)cl * N];
            }
    }
}

extern "C" void kernel_launch(void* const* d_in, const int* in_sizes, int n_in,
                              void* d_out, int out_size, void* d_ws, size_t ws_size,
                              hipStream_t stream) {
    const float* x     = (const float*)d_in[0];
    const float* Wf_w  = (const float*)d_in[1];
    const float* Wf_b  = (const float*)d_in[2];
    const float* Wh_w  = (const float*)d_in[3];
    const float* Wh_b  = (const float*)d_in[4];
    const float* Wl_w  = (const float*)d_in[5];
    const float* Wl_b  = (const float*)d_in[6];
    const float* alpha = (const float*)d_in[7];
    char* ws = (char*)d_ws;
    f16*   ftb  = (f16*)(ws + WS_FT);
    f16*   ktb  = (f16*)(ws + WS_KT);
    f16*   vb   = (f16*)(ws + WS_V);
    f16*   wall = (f16*)(ws + WS_WALL);
    float* ball = (float*)(ws + WS_BALL);
    float* out  = (float*)d_out;

    prep_weights<<<dim3((OALL * C + 255) / 256), dim3(256), 0, stream>>>(Wf_w, Wf_b, Wh_w, Wh_b, Wl_w, Wl_b, wall, ball);
    // fused projections: 4 b x 64 n-tiles x 2 o-halves = 512 blocks x 4 waves
    proj_all<<<dim3(512), dim3(256), 0, stream>>>(x, wall, ball, ftb, ktb, vb);
    // 4 b x 64 query-tiles(64q) = 256 blocks x 8 waves = 1 block/CU, XCD-pinned
    attn<<<dim3(256), dim3(512), 0, stream>>>(ftb, ktb, vb, x, alpha, out);
}

// Round 22
// 167.078 us; speedup vs baseline: 1.0306x; 1.0049x over previous
//
#include <hip/hip_runtime.h>
#include <hip/hip_bf16.h>

typedef _Float16 f16;
typedef _Float16 f16x4 __attribute__((ext_vector_type(4)));
typedef _Float16 f16x8 __attribute__((ext_vector_type(8)));
typedef float f32x4 __attribute__((ext_vector_type(4)));

constexpr int BATCH = 4, C = 512, CQ = 128, N = 4096;
constexpr int OALL = 768; // stacked outputs: f(128) + k(128) + v(512)

// workspace layout (bytes)
constexpr size_t WS_FT   = 0;                                      // f16 [B][N][128]       4 MB
constexpr size_t WS_KT   = WS_FT   + (size_t)BATCH * N * CQ * 2;   // f16 [B][N][128]       4 MB (K, row-major)
constexpr size_t WS_V    = WS_KT   + (size_t)BATCH * N * CQ * 2;   // f16 [B][C/16][N/8][16][8] 16 MB (tiled V)
constexpr size_t WS_WALL = WS_V    + (size_t)BATCH * C * N * 2;    // f16 [768][512]
constexpr size_t WS_BALL = WS_WALL + (size_t)OALL * C * 2;         // f32 [768]

// ---------------------------------------------------------------- stacked weights->fp16
__global__ void prep_weights(const float* __restrict__ Wf_w, const float* __restrict__ Wf_b,
                             const float* __restrict__ Wh_w, const float* __restrict__ Wh_b,
                             const float* __restrict__ Wl_w, const float* __restrict__ Wl_b,
                             f16* __restrict__ wall, float* __restrict__ ball) {
    int i = blockIdx.x * 256 + threadIdx.x;                 // grid covers 768*512
    if (i < OALL * C) {
        int o = i >> 9, c = i & 511;
        float v = (o < 128) ? Wf_w[o * C + c]
                : (o < 256) ? Wh_w[(o - 128) * C + c]
                            : Wl_w[(o - 256) * C + c];
        wall[i] = (f16)v;
    }
    if (i < OALL)
        ball[i] = (i < 128) ? Wf_b[i] : (i < 256) ? Wh_b[i - 128] : Wl_b[i - 256];
}

// ---------------------------------------------------------------- fused projections (v16 champion)
// One kernel replaces transpose_x + proj_fk + proj_v. Block = 512 thr (8 waves),
// one (b, 64n) tile. Per 64-c chunk: stage x[64c][64n] f32 -> LDS f16 transposed
// [64n][72c]; each wave computes its 96-o slice of stacked W (768x512, L2-res).
__global__ void __launch_bounds__(512) proj_all(const float* __restrict__ x, const f16* __restrict__ wall,
                                                const float* __restrict__ ball,
                                                f16* __restrict__ ft, f16* __restrict__ kt,
                                                f16* __restrict__ v) {
    __shared__ __align__(16) f16 xl[64][72];   // 9 KB, 72-pad for b128 alignment
    const int tid = threadIdx.x;
    const int wv  = tid >> 6;
    const int lane = tid & 63;
    const int li = lane & 15, lg = lane >> 4;
    const int b  = blockIdx.x >> 6;
    const int n0 = (blockIdx.x & 63) * 64;
    const int ob = wv * 96;                    // wave's output slice (6 frags of 16)
    const int nn = tid & 63, cg = tid >> 6;    // staging decode: 8 c-groups of 8

    f32x4 acc[6][4] = {};                      // [o-frag][n-frag]
    for (int ch = 0; ch < 8; ++ch) {
        __syncthreads();                       // xl free (readers of prev chunk done)
        {   // stage 64c x 64n f32 -> xl[n][c] f16 (global reads coalesced along n)
            const float* xs = x + ((size_t)(b * C) + ch * 64 + cg * 8) * N + n0 + nn;
#pragma unroll
            for (int r = 0; r < 8; ++r)
                xl[nn][cg * 8 + r] = (f16)xs[(size_t)r * N];
        }
        __syncthreads();
#pragma unroll
        for (int ks = 0; ks < 2; ++ks) {
            f16x8 xfr[4];
#pragma unroll
            for (int nf = 0; nf < 4; ++nf)
                xfr[nf] = *(const f16x8*)(&xl[nf * 16 + li][ks * 32 + lg * 8]);
#pragma unroll
            for (int of = 0; of < 6; ++of) {
                f16x8 wfr = *(const f16x8*)(wall + (size_t)(ob + of * 16 + li) * C + ch * 64 + ks * 32 + lg * 8);
#pragma unroll
                for (int nf = 0; nf < 4; ++nf)
                    acc[of][nf] = __builtin_amdgcn_mfma_f32_16x16x32_f16(xfr[nf], wfr, acc[of][nf], 0, 0, 0);
            }
        }
    }
    // epilogue: D col(li) = o (B-operand row), D row (lg*4+r) = n (A-operand row)
#pragma unroll
    for (int of = 0; of < 6; ++of) {
        const int o = ob + of * 16 + li;
        const float bias = ball[o];
#pragma unroll
        for (int nf = 0; nf < 4; ++nf)
#pragma unroll
            for (int r = 0; r < 4; ++r) {
                const int n = n0 + nf * 16 + lg * 4 + r;
                const f16 val = (f16)(acc[of][nf][r] + bias);
                if (o < 128) {
                    ft[(size_t)(b * N + n) * CQ + o] = val;
                } else if (o < 256) {
                    const int ck = o - 128;
                    kt[((size_t)b * N + n) * 128 + ck] = val;
                } else {
                    const int c = o - 256;
                    v[(((size_t)b * 32 + (c >> 4)) * 512 + (n >> 3)) * 128 + (c & 15) * 8 + (n & 7)] = val;
                }
            }
    }
}

// ---------------------------------------------------------------- flash attention + residual (v17 champion)
// Direct-register K double-buffer (no LDS round-trip), 2 barriers/iter,
// shared-stats softmax (scalar broadcast layout), rolling V prefetch,
// 256 blocks XCD-pinned, tiled kt/V operands (1KB contiguous loads).
__global__ void __launch_bounds__(512, 2) attn(const f16* __restrict__ ft, const f16* __restrict__ kt,
                                               const f16* __restrict__ v,
                                               const float* __restrict__ x, const float* __restrict__ alphap,
                                               float* __restrict__ out) {
    __shared__ __align__(16) f16 pbuf[64 * 128];       // 16 KB shared P
    __shared__ float smax[8][4][16];
    __shared__ float ssum[8][4][16];

    const int tid  = threadIdx.x;
    const int wv   = tid >> 6;
    const int lane = tid & 63;
    const int li = lane & 15, lg = lane >> 4;
    const int swl = li & 7;
    // XCD-pinning: under blk%8 round-robin, each XCD sees a single batch
    const int v0 = blockIdx.x;
    const int b  = (v0 & 7) >> 1;
    const int it = ((v0 & 1) << 5) | (v0 >> 3);
    const int i0 = it * 64;
    const int c0 = wv * 64;

    // F fragments (B operand of swapped QK): col=i, k=ck; 4 i-frags
    f16x8 fb[4][4];
#pragma unroll
    for (int f = 0; f < 4; ++f) {
        const f16* fp = ft + (size_t)(b * N + i0 + f * 16 + li) * CQ + lg * 8;
#pragma unroll
        for (int ks = 0; ks < 4; ++ks) fb[f][ks] = *(const f16x8*)(fp + ks * 32);
    }

    // direct-register K: lane reads row (t*128 + wv*16 + li), cols ks*32 + lg*8
    const f16* kL = kt + ((size_t)b * N + wv * 16 + li) * 128 + lg * 8;
    f16x8 kf[4];
#pragma unroll
    for (int ks = 0; ks < 4; ++ks) kf[ks] = *(const f16x8*)(kL + ks * 32);

    // tiled V base: fragment (cf, phase) at vb2 + (cf*512 + t*16 + ph*4)*128
    const f16* vb2 = v + (((size_t)b * 32 + wv * 4) * 512 + lg) * 128 + li * 8;
    f32x4 oacc[4][4] = {};                       // [c-frag][i-frag]
    float ms[4] = {-1e30f, -1e30f, -1e30f, -1e30f};
    float ls[4] = {0.f, 0.f, 0.f, 0.f};

    for (int t = 0; t < 32; ++t) {
        const size_t jb0 = (size_t)t * 16;
        // (a) prefetch next K tile fragments into kfn (whole iteration of cover)
        f16x8 kfn[4];
        const size_t knext = (size_t)((t < 31) ? (t + 1) : 0) * 128 * 128;
#pragma unroll
        for (int ks = 0; ks < 4; ++ks) kfn[ks] = *(const f16x8*)(kL + knext + ks * 32);

        // (b) QK for this wave's 16-j slice, all 4 i-frags (K from registers)
        f32x4 s[4] = {};
        __builtin_amdgcn_s_setprio(1);
#pragma unroll
        for (int ks = 0; ks < 4; ++ks)
#pragma unroll
            for (int f = 0; f < 4; ++f)
                s[f] = __builtin_amdgcn_mfma_f32_16x16x32_f16(kf[ks], fb[f][ks], s[f], 0, 0, 0);
        __builtin_amdgcn_s_setprio(0);

        // (c) wave-local max per query (rows j = wv*16 + lg*4 + r)
#pragma unroll
        for (int f = 0; f < 4; ++f) {
            float t0 = fmaxf(fmaxf(s[f][0], s[f][1]), fmaxf(s[f][2], s[f][3]));
            t0 = fmaxf(t0, __shfl_xor(t0, 16));
            t0 = fmaxf(t0, __shfl_xor(t0, 32));
            if (lane < 16) smax[wv][f][li] = t0;
        }
        // V prefetch for PV kf=0, issued before the barrier (latency hides under it)
        f16x8 va[2][4];
#pragma unroll
        for (int cf = 0; cf < 4; ++cf) va[0][cf] = *(const f16x8*)(vb2 + ((size_t)cf * 512 + jb0) * 128);
        __syncthreads();   // B1: max stats visible
        // (d) tile max over 8 waves (broadcast reads)
        float gm[4];
#pragma unroll
        for (int f = 0; f < 4; ++f) {
            float m0 = smax[0][f][li];
#pragma unroll
            for (int w = 1; w < 8; ++w) m0 = fmaxf(m0, smax[w][f][li]);
            gm[f] = m0;
        }
        // V prefetch for kf=1
#pragma unroll
        for (int cf = 0; cf < 4; ++cf) va[1][cf] = *(const f16x8*)(vb2 + ((size_t)cf * 512 + jb0 + 4) * 128);
        // T13 deferred rescale (identical decision in all waves: shared stats)
#pragma unroll
        for (int f = 0; f < 4; ++f) {
            if (!__all(gm[f] <= ms[f] + 8.0f)) {
                float mn = fmaxf(ms[f], gm[f]), sc = __expf(ms[f] - mn);
                ms[f] = mn; ls[f] *= sc;
#pragma unroll
                for (int cf = 0; cf < 4; ++cf) oacc[cf][f] *= sc;
            }
        }
        // exp (this wave's 4 j per lane per f) + P write + partial sums
        const int jl = wv * 16 + lg * 4;
        const int gg = (jl >> 3) ^ swl;
        float ps[4];
#pragma unroll
        for (int f = 0; f < 4; ++f) {
            f16x4 pk;
            float p0 = 0.f;
#pragma unroll
            for (int r = 0; r < 4; ++r) { float p = __expf(s[f][r] - ms[f]); p0 += p; pk[r] = (f16)p; }
            *(f16x4*)(&pbuf[(f * 16 + li) * 128 + gg * 8 + (jl & 7)]) = pk;
            ps[f] = p0;
        }
#pragma unroll
        for (int f = 0; f < 4; ++f) {
            ps[f] += __shfl_xor(ps[f], 16);
            ps[f] += __shfl_xor(ps[f], 32);
        }
        if (lane < 16) {
#pragma unroll
            for (int f = 0; f < 4; ++f) ssum[wv][f][li] = ps[f];
        }
        __syncthreads();   // B2: P + ssum visible
        // (f) accumulate l from shared partial sums
#pragma unroll
        for (int f = 0; f < 4; ++f) {
            float a0 = 0.f;
#pragma unroll
            for (int w = 0; w < 8; ++w) a0 += ssum[w][f][li];
            ls[f] += a0;
        }
        // (g) PV over full 128 j, this wave's 64 channels; rolling V prefetch
#pragma unroll
        for (int kf2 = 0; kf2 < 4; ++kf2) {
            const int cur = kf2 & 1;
            const int g = (kf2 * 4 + lg) ^ swl;
            f16x8 pb[4];
#pragma unroll
            for (int f = 0; f < 4; ++f)
                pb[f] = *(const f16x8*)(&pbuf[(f * 16 + li) * 128 + g * 8]);
            f16x8 vv0 = va[cur][0], vv1 = va[cur][1], vv2 = va[cur][2], vv3 = va[cur][3];
            if (kf2 < 2) {
#pragma unroll
                for (int cf = 0; cf < 4; ++cf)
                    va[cur][cf] = *(const f16x8*)(vb2 + ((size_t)cf * 512 + jb0 + (kf2 + 2) * 4) * 128);
            }
            __builtin_amdgcn_s_setprio(1);
#pragma unroll
            for (int f = 0; f < 4; ++f) {
                oacc[0][f] = __builtin_amdgcn_mfma_f32_16x16x32_f16(vv0, pb[f], oacc[0][f], 0, 0, 0);
                oacc[1][f] = __builtin_amdgcn_mfma_f32_16x16x32_f16(vv1, pb[f], oacc[1][f], 0, 0, 0);
                oacc[2][f] = __builtin_amdgcn_mfma_f32_16x16x32_f16(vv2, pb[f], oacc[2][f], 0, 0, 0);
                oacc[3][f] = __builtin_amdgcn_mfma_f32_16x16x32_f16(vv3, pb[f], oacc[3][f], 0, 0, 0);
            }
            __builtin_amdgcn_s_setprio(0);
        }
        // roll K double-buffer
#pragma unroll
        for (int ks = 0; ks < 4; ++ks) kf[ks] = kfn[ks];
        // no 3rd barrier: next iter's B1 orders pbuf reuse (same proof as v12)
    }

    // epilogue: O[c][i], i coalesced over li; + residual
    const float alpha = alphap[0];
#pragma unroll
    for (int f = 0; f < 4; ++f) {
        const float invf = alpha / ls[f];
        const float* xp = x + (size_t)(b * C + c0) * N + i0 + f * 16 + li;
        float* op = out + (size_t)(b * C + c0) * N + i0 + f * 16 + li;
#pragma unroll
        for (int cf = 0; cf < 4; ++cf)
#pragma unroll
            for (int r = 0; r < 4; ++r) {
                const int cl = cf * 16 + lg * 4 + r;
                op[(size_t)cl * N] = oacc[cf][f][r] * invf + xp[(size_t)cl * N];
            }
    }
}

extern "C" void kernel_launch(void* const* d_in, const int* in_sizes, int n_in,
                              void* d_out, int out_size, void* d_ws, size_t ws_size,
                              hipStream_t stream) {
    const float* x     = (const float*)d_in[0];
    const float* Wf_w  = (const float*)d_in[1];
    const float* Wf_b  = (const float*)d_in[2];
    const float* Wh_w  = (const float*)d_in[3];
    const float* Wh_b  = (const float*)d_in[4];
    const float* Wl_w  = (const float*)d_in[5];
    const float* Wl_b  = (const float*)d_in[6];
    const float* alpha = (const float*)d_in[7];
    char* ws = (char*)d_ws;
    f16*   ftb  = (f16*)(ws + WS_FT);
    f16*   ktb  = (f16*)(ws + WS_KT);
    f16*   vb   = (f16*)(ws + WS_V);
    f16*   wall = (f16*)(ws + WS_WALL);
    float* ball = (float*)(ws + WS_BALL);
    float* out  = (float*)d_out;

    prep_weights<<<dim3((OALL * C + 255) / 256), dim3(256), 0, stream>>>(Wf_w, Wf_b, Wh_w, Wh_b, Wl_w, Wl_b, wall, ball);
    // fused projections: 4 b x 64 n-tiles = 256 blocks x 8 waves
    proj_all<<<dim3(256), dim3(512), 0, stream>>>(x, wall, ball, ftb, ktb, vb);
    // 4 b x 64 query-tiles(64q) = 256 blocks x 8 waves = 1 block/CU, XCD-pinned
    attn<<<dim3(256), dim3(512), 0, stream>>>(ftb, ktb, vb, x, alpha, out);
}